// Round 1
// baseline (11169.312 us; speedup 1.0000x reference)
//
#include <hip/hip_runtime.h>
#include <math.h>

#define HH 256
#define WW 256
#define HW 65536
#define BB 4
#define NL 5
#define HID_C 100

constexpr float SLOPE_C = 0.01f;

__device__ __forceinline__ float leaky_f(float x){ return x >= 0.f ? x : SLOPE_C * x; }

// ---------------------------------------------------------------------------
// init: images[0]=source, residuals[0]=broadcast(z0), def=identity grid
// ---------------------------------------------------------------------------
__global__ void k_init(const float* __restrict__ src, const float* __restrict__ z0,
                       float* __restrict__ images0, float* __restrict__ resid0,
                       float* __restrict__ def){
    int p = blockIdx.x * 256 + threadIdx.x;      // 0 .. B*HW
    int b = p >> 16, q = p & 65535;
    images0[p] = src[p];
    resid0[p]  = z0[q];
    int x = q & 255, y = q >> 8;
    def[(size_t)(b * 2 + 0) * HW + q] = (float)x;
    def[(size_t)(b * 2 + 1) * HW + q] = (float)y;
}

// ---------------------------------------------------------------------------
// spatial gradient (Sobel/8, edge padding). gout = grads slot base (B,2,HW)
// ---------------------------------------------------------------------------
__global__ void k_grad(const float* __restrict__ img, float* __restrict__ gout){
    int p = blockIdx.x * 256 + threadIdx.x;
    int b = p >> 16, q = p & 65535;
    int x = q & 255, y = q >> 8;
    const float* ib = img + (size_t)b * HW;
    int xm = max(x - 1, 0), xp = min(x + 1, 255);
    int ym = max(y - 1, 0), yp = min(y + 1, 255);
    float a00 = ib[ym * 256 + xm], a01 = ib[ym * 256 + x], a02 = ib[ym * 256 + xp];
    float a10 = ib[y  * 256 + xm],                         a12 = ib[y  * 256 + xp];
    float a20 = ib[yp * 256 + xm], a21 = ib[yp * 256 + x], a22 = ib[yp * 256 + xp];
    float gx = (a02 - a00 + 2.f * (a12 - a10) + a22 - a20) * 0.125f;
    float gy = (a20 - a00 + 2.f * (a21 - a01) + a22 - a02) * 0.125f;
    gout[(size_t)(b * 2 + 0) * HW + q] = gx;
    gout[(size_t)(b * 2 + 1) * HW + q] = gy;
}

// ---------------------------------------------------------------------------
// pack 3 channels into contiguous (B,3,HW) buffer
// ---------------------------------------------------------------------------
__global__ void k_pack3(const float* __restrict__ a, int sa,
                        const float* __restrict__ bc, int sb,
                        const float* __restrict__ c, int sc,
                        float* __restrict__ dst){
    int p = blockIdx.x * 256 + threadIdx.x;
    int b = p >> 16, q = p & 65535;
    dst[(size_t)(b * 3 + 0) * HW + q] = a [(size_t)b * sa + q];
    dst[(size_t)(b * 3 + 1) * HW + q] = bc[(size_t)b * sb + q];
    dst[(size_t)(b * 3 + 2) * HW + q] = c [(size_t)b * sc + q];
}

// ---------------------------------------------------------------------------
// Tiled 3x3 conv (pad 1). 32x32 output tile, 4 px/thread in x, OCB oc/block.
// in: (bz, CIN, HW) chunk-local.  w: (OC, CIN, 3, 3).
// EPI 0: out h-layout (bz*100+oc)*HW with leaky
// EPI 1: (OCB==1) out = rprev + acc*0.2 -> outp[b*HW], rd[b*HW]   (z conv3)
// EPI 2: out vtmp (b*2+oc)*HW raw                                  (v conv3)
// ---------------------------------------------------------------------------
template<int CIN, int OCB, int EPI>
__global__ __launch_bounds__(256)
void k_conv(const float* __restrict__ in, const float* __restrict__ w,
            float* __restrict__ outp, const float* __restrict__ rprev,
            float* __restrict__ rd, int b0){
    __shared__ float tile[34 * 37];
    const int tid = threadIdx.x;
    const int tileX = blockIdx.x & 7, tileY = blockIdx.x >> 3;
    const int oc0 = blockIdx.y * OCB;
    const int bz = blockIdx.z;
    const int tx = tid & 7, ty = tid >> 3;

    float acc[OCB][4];
    #pragma unroll
    for (int k = 0; k < OCB; k++)
        #pragma unroll
        for (int px = 0; px < 4; px++) acc[k][px] = 0.f;

    const float* inb = in + (size_t)bz * CIN * HW;

    for (int ic = 0; ic < CIN; ic++){
        __syncthreads();
        for (int idx = tid; idx < 34 * 34; idx += 256){
            int r = idx / 34, c = idx - r * 34;
            int gy = tileY * 32 + r - 1, gx = tileX * 32 + c - 1;
            float v = 0.f;
            if (gy >= 0 && gy < 256 && gx >= 0 && gx < 256)
                v = inb[(size_t)ic * HW + gy * 256 + gx];
            tile[r * 37 + c] = v;
        }
        __syncthreads();

        float rowv[3][6];
        #pragma unroll
        for (int dr = 0; dr < 3; dr++)
            #pragma unroll
            for (int dc = 0; dc < 6; dc++)
                rowv[dr][dc] = tile[(ty + dr) * 37 + tx * 4 + dc];

        const float* wic = w + (size_t)(oc0 * CIN + ic) * 9;
        #pragma unroll
        for (int k = 0; k < OCB; k++){
            const float* wk = wic + (size_t)k * CIN * 9;   // uniform -> s_load
            #pragma unroll
            for (int dr = 0; dr < 3; dr++)
                #pragma unroll
                for (int dc = 0; dc < 3; dc++){
                    float wv = wk[dr * 3 + dc];
                    #pragma unroll
                    for (int px = 0; px < 4; px++)
                        acc[k][px] = fmaf(wv, rowv[dr][px + dc], acc[k][px]);
                }
        }
    }

    const int xo = tileX * 32 + tx * 4;
    const int yo = tileY * 32 + ty;
    const size_t p = (size_t)yo * 256 + xo;

    if (EPI == 0){
        #pragma unroll
        for (int k = 0; k < OCB; k++){
            float4 v = make_float4(leaky_f(acc[k][0]), leaky_f(acc[k][1]),
                                   leaky_f(acc[k][2]), leaky_f(acc[k][3]));
            *(float4*)(outp + ((size_t)(bz * 100 + oc0 + k)) * HW + p) = v;
        }
    } else if (EPI == 1){
        const int b = b0 + bz;
        float4 rp = *(const float4*)(rprev + (size_t)b * HW + p);
        float4 v = make_float4(rp.x + acc[0][0] * 0.2f, rp.y + acc[0][1] * 0.2f,
                               rp.z + acc[0][2] * 0.2f, rp.w + acc[0][3] * 0.2f);
        *(float4*)(outp + (size_t)b * HW + p) = v;
        *(float4*)(rd   + (size_t)b * HW + p) = v;
    } else {
        const int b = b0 + bz;
        #pragma unroll
        for (int k = 0; k < OCB; k++){
            float4 v = make_float4(acc[k][0], acc[k][1], acc[k][2], acc[k][3]);
            *(float4*)(outp + ((size_t)(b * 2 + oc0 + k)) * HW + p) = v;
        }
    }
}

// ---------------------------------------------------------------------------
// bilinear sample with zero-outside tap masking (matches reference taps)
// ---------------------------------------------------------------------------
__device__ __forceinline__ float bilin(const float* __restrict__ img, float x, float y){
    float x0 = floorf(x), y0 = floorf(y);
    float wx = x - x0, wy = y - y0;
    float r = 0.f;
    #pragma unroll
    for (int dy = 0; dy < 2; dy++){
        float yi = y0 + (float)dy;
        if (yi < 0.f || yi > 255.f) continue;
        int iy = (int)yi;
        float wyv = dy ? wy : 1.f - wy;
        #pragma unroll
        for (int dx = 0; dx < 2; dx++){
            float xi = x0 + (float)dx;
            if (xi < 0.f || xi > 255.f) continue;
            int ix = (int)xi;
            float wxv = dx ? wx : 1.f - wx;
            r += wyv * wxv * img[iy * 256 + ix];
        }
    }
    return r;
}

// deform RD entries: rdout[j] = bilin(rdin[j], def)   (grid.y = j count)
__global__ void k_deform(const float* __restrict__ rdin, const float* __restrict__ def,
                         float* __restrict__ rdout){
    int p = blockIdx.x * 256 + threadIdx.x;
    int j = blockIdx.y;
    int b = p >> 16, q = p & 65535;
    float x = def[(size_t)(b * 2 + 0) * HW + q];
    float y = def[(size_t)(b * 2 + 1) * HW + q];
    rdout[(size_t)j * BB * HW + p] = bilin(rdin + (size_t)j * BB * HW + (size_t)b * HW, x, y);
}

// ---------------------------------------------------------------------------
// horizontal 51-tap gaussian blur (zero pad), one row per block
// ---------------------------------------------------------------------------
__global__ void k_blur_h(const float* __restrict__ in, float* __restrict__ outb){
    __shared__ float g[51];
    __shared__ float row[306];
    __shared__ float ginv;
    int tid = threadIdx.x;
    int rid = blockIdx.x;          // 0 .. B*2*256-1
    int ch = rid >> 8, y = rid & 255;
    if (tid < 51){ float d = (float)tid - 25.f; g[tid] = expf(-0.005f * d * d); }
    row[tid + 25] = in[(size_t)ch * HW + y * 256 + tid];
    if (tid < 25) row[tid] = 0.f;
    if (tid >= 231) row[tid + 50] = 0.f;
    __syncthreads();
    if (tid == 0){ float s = 0.f; for (int k = 0; k < 51; k++) s += g[k]; ginv = 1.f / s; }
    __syncthreads();
    float acc = 0.f;
    for (int k = 0; k < 51; k++) acc = fmaf(g[k], row[tid + k], acc);
    outb[(size_t)ch * HW + y * 256 + tid] = acc * ginv;
}

// ---------------------------------------------------------------------------
// vertical 51-tap blur + write fields slot + def -= field/5.  tile 64w x 32h
// grid: (4, 8, 8)  block 256
// ---------------------------------------------------------------------------
__global__ void k_blur_v(const float* __restrict__ in, float* __restrict__ fout,
                         float* __restrict__ def){
    __shared__ float g[51];
    __shared__ float ginv;
    __shared__ float tb[82 * 64];
    int tid = threadIdx.x;
    int tX = blockIdx.x, tY = blockIdx.y, ch = blockIdx.z;
    if (tid < 51){ float d = (float)tid - 25.f; g[tid] = expf(-0.005f * d * d); }
    for (int idx = tid; idx < 82 * 64; idx += 256){
        int r = idx >> 6, c = idx & 63;
        int gy = tY * 32 + r - 25, gx = tX * 64 + c;
        tb[idx] = (gy >= 0 && gy < 256) ? in[(size_t)ch * HW + gy * 256 + gx] : 0.f;
    }
    __syncthreads();
    if (tid == 0){ float s = 0.f; for (int k = 0; k < 51; k++) s += g[k]; ginv = 1.f / s; }
    __syncthreads();
    int c = tid & 63, r0 = (tid >> 6) * 8;
    for (int k = 0; k < 8; k++){
        int r = r0 + k;
        float acc = 0.f;
        for (int t = 0; t < 51; t++) acc = fmaf(g[t], tb[(r + t) * 64 + c], acc);
        acc *= ginv;
        int y = tY * 32 + r, x = tX * 64 + c;
        fout[(size_t)ch * HW + y * 256 + x] = acc;
        def [(size_t)ch * HW + y * 256 + x] -= acc * 0.2f;
    }
}

// ---------------------------------------------------------------------------
// fused: mask = warp(seg,def); src_s = warp(source,def); acc = sum RD[0..nrd-1]
// images[i+1] = src_s + acc * 8e-5 * mask
// ---------------------------------------------------------------------------
__global__ void k_final(const float* __restrict__ def, const float* __restrict__ src,
                        const float* __restrict__ seg, const float* __restrict__ rdbase,
                        int nrd, float* __restrict__ imgout){
    int p = blockIdx.x * 256 + threadIdx.x;
    int b = p >> 16, q = p & 65535;
    float x = def[(size_t)(b * 2 + 0) * HW + q];
    float y = def[(size_t)(b * 2 + 1) * HW + q];
    float m = bilin(seg + (size_t)b * HW, x, y);
    float s = bilin(src + (size_t)b * HW, x, y);
    float acc = 0.f;
    for (int j = 0; j < nrd; j++) acc += rdbase[(size_t)j * BB * HW + p];
    imgout[p] = s + acc * 8e-5f * m;
}

// ---------------------------------------------------------------------------
extern "C" void kernel_launch(void* const* d_in, const int* in_sizes, int n_in,
                              void* d_out, int out_size, void* d_ws, size_t ws_size,
                              hipStream_t stream){
    const float* source = (const float*)d_in[0];
    const float* seg    = (const float*)d_in[1];
    const float* z0     = (const float*)d_in[2];
    const float* zw1    = (const float*)d_in[3];
    const float* zw2    = (const float*)d_in[4];
    const float* zw3    = (const float*)d_in[5];
    const float* vw1    = (const float*)d_in[6];
    const float* vw2    = (const float*)d_in[7];
    const float* vw3    = (const float*)d_in[8];

    float* out = (float*)d_out;
    float* images = out;                       // (6,B,1,HW)
    float* fields = out + 1572864;             // (5,B,2,HW)
    float* resid  = out + 4194304;             // (6,B,1,HW)
    float* grads  = out + 5767168;             // (6,B,2,HW)

    float* ws = (float*)d_ws;
    size_t off = 0;
    float* def  = ws + off; off += (size_t)BB * 2 * HW;        // 524288
    float* RDa  = ws + off; off += (size_t)NL * BB * HW;       // 1310720
    float* RDb  = ws + off; off += (size_t)NL * BB * HW;
    float* vtmp = ws + off; off += (size_t)BB * 2 * HW;
    float* btmp = ws + off; off += (size_t)BB * 2 * HW;
    float* pk3  = ws + off; off += (size_t)BB * 3 * HW;
    float* h1   = ws + off;

    size_t full_bytes = (off + 2ull * BB * 100 * HW) * 4;
    const int HB = (ws_size >= full_bytes) ? BB : 1;
    float* h2 = h1 + (size_t)HB * 100 * HW;

    k_init<<<1024, 256, 0, stream>>>(source, z0, images, resid, def);
    k_grad<<<1024, 256, 0, stream>>>(source, grads);

    float* RDcur = RDa;
    float* RDnxt = RDb;

    for (int i = 0; i < NL; i++){
        float* res_i  = resid  + (size_t)i * BB * HW;
        float* res_ip = resid  + (size_t)(i + 1) * BB * HW;
        float* img_i  = images + (size_t)i * BB * HW;
        float* img_ip = images + (size_t)(i + 1) * BB * HW;

        // ---- Phase A: z residual path ----
        k_pack3<<<1024, 256, 0, stream>>>(res_i, HW, img_i, HW, images, HW, pk3);
        for (int b0 = 0; b0 < BB; b0 += HB){
            k_conv<3, 20, 0><<<dim3(64, 5, HB), 256, 0, stream>>>(
                pk3 + (size_t)b0 * 3 * HW, zw1 + (size_t)i * 2700, h1, nullptr, nullptr, b0);
            k_conv<100, 20, 0><<<dim3(64, 5, HB), 256, 0, stream>>>(
                h1, zw2 + (size_t)i * 90000, h2, nullptr, nullptr, b0);
            k_conv<100, 1, 1><<<dim3(64, 1, HB), 256, 0, stream>>>(
                h2, zw3 + (size_t)i * 900, res_ip, res_i, RDnxt + (size_t)i * BB * HW, b0);
        }

        // ---- Phase B: deform previous deformed residuals (pre-update def) ----
        if (i > 0)
            k_deform<<<dim3(1024, i), 256, 0, stream>>>(RDcur, def, RDnxt);

        // ---- Phase C: v field path ----
        k_pack3<<<1024, 256, 0, stream>>>(def, 2 * HW, def + HW, 2 * HW, img_i, HW, pk3);
        for (int b0 = 0; b0 < BB; b0 += HB){
            k_conv<3, 20, 0><<<dim3(64, 5, HB), 256, 0, stream>>>(
                pk3 + (size_t)b0 * 3 * HW, vw1 + (size_t)i * 2700, h1, nullptr, nullptr, b0);
            k_conv<100, 20, 0><<<dim3(64, 5, HB), 256, 0, stream>>>(
                h1, vw2 + (size_t)i * 90000, h2, nullptr, nullptr, b0);
            k_conv<100, 2, 2><<<dim3(64, 1, HB), 256, 0, stream>>>(
                h2, vw3 + (size_t)i * 1800, vtmp, nullptr, nullptr, b0);
        }
        k_blur_h<<<2048, 256, 0, stream>>>(vtmp, btmp);
        k_blur_v<<<dim3(4, 8, 8), 256, 0, stream>>>(btmp, fields + (size_t)i * BB * 2 * HW, def);

        // ---- finalize: mask, acc, new image, gradient ----
        k_final<<<1024, 256, 0, stream>>>(def, source, seg, RDnxt, i + 1, img_ip);
        k_grad<<<1024, 256, 0, stream>>>(img_ip, grads + (size_t)(i + 1) * BB * 2 * HW);

        float* t = RDcur; RDcur = RDnxt; RDnxt = t;
    }
}

// Round 2
// 2332.251 us; speedup vs baseline: 4.7891x; 4.7891x over previous
//
#include <hip/hip_runtime.h>
#include <math.h>

#define HW 65536
#define BB 4
#define NL 5

typedef short s8v __attribute__((ext_vector_type(8)));
typedef float f4v __attribute__((ext_vector_type(4)));
typedef unsigned short u16;

__device__ __forceinline__ float leaky_f(float x){ return x >= 0.f ? x : 0.01f * x; }

__device__ __forceinline__ u16 f2bf(float x){
    union { float f; unsigned u; } v; v.f = x;
    unsigned r = v.u + 0x7FFF + ((v.u >> 16) & 1);
    return (u16)(r >> 16);
}
__device__ __forceinline__ float bf2f(u16 h){
    union { unsigned u; float f; } v; v.u = ((unsigned)h) << 16;
    return v.f;
}

// ---------------------------------------------------------------------------
// init: images[0]=source, residuals[0]=broadcast(z0), def=identity grid
// ---------------------------------------------------------------------------
__global__ void k_init(const float* __restrict__ src, const float* __restrict__ z0,
                       float* __restrict__ images0, float* __restrict__ resid0,
                       float* __restrict__ def){
    int p = blockIdx.x * 256 + threadIdx.x;
    int b = p >> 16, q = p & 65535;
    images0[p] = src[p];
    resid0[p]  = z0[q];
    int x = q & 255, y = q >> 8;
    def[(size_t)(b * 2 + 0) * HW + q] = (float)x;
    def[(size_t)(b * 2 + 1) * HW + q] = (float)y;
}

// ---------------------------------------------------------------------------
// spatial gradient (Sobel/8, edge padding)
// ---------------------------------------------------------------------------
__global__ void k_grad(const float* __restrict__ img, float* __restrict__ gout){
    int p = blockIdx.x * 256 + threadIdx.x;
    int b = p >> 16, q = p & 65535;
    int x = q & 255, y = q >> 8;
    const float* ib = img + (size_t)b * HW;
    int xm = max(x - 1, 0), xp = min(x + 1, 255);
    int ym = max(y - 1, 0), yp = min(y + 1, 255);
    float a00 = ib[ym * 256 + xm], a01 = ib[ym * 256 + x], a02 = ib[ym * 256 + xp];
    float a10 = ib[y  * 256 + xm],                         a12 = ib[y  * 256 + xp];
    float a20 = ib[yp * 256 + xm], a21 = ib[yp * 256 + x], a22 = ib[yp * 256 + xp];
    float gx = (a02 - a00 + 2.f * (a12 - a10) + a22 - a20) * 0.125f;
    float gy = (a20 - a00 + 2.f * (a21 - a01) + a22 - a02) * 0.125f;
    gout[(size_t)(b * 2 + 0) * HW + q] = gx;
    gout[(size_t)(b * 2 + 1) * HW + q] = gy;
}

// ---------------------------------------------------------------------------
// pack conv2 weights (z+v, 5 layers) into MFMA B-fragment order, bf16.
// chunk = ((path*5+layer)*9+off)*28 + ks*7 + nt ; within chunk: lane*8+j
// B[n=lane&15][k=quad*8+j], ic padded->128 (k), oc padded->112 (n)
// ---------------------------------------------------------------------------
__global__ void k_packw(const float* __restrict__ zw2, const float* __restrict__ vw2,
                        u16* __restrict__ wp){
    int idx = blockIdx.x * 256 + threadIdx.x;     // < 1,290,240
    int lane9 = idx & 511, chunk = idx >> 9;
    int nt = chunk % 7; int t = chunk / 7;
    int ks = t % 4; t >>= 2;
    int off = t % 9; t /= 9;
    int layer = t % 5, path = t / 5;
    int lane = lane9 >> 3, j = lane9 & 7;
    int ic = ks * 32 + (lane >> 4) * 8 + j;
    int oc = nt * 16 + (lane & 15);
    const float* w = path ? vw2 : zw2;
    float v = 0.f;
    if (ic < 100 && oc < 100)
        v = w[(((size_t)layer * 100 + oc) * 100 + ic) * 9 + off];
    wp[idx] = f2bf(v);
}

// ---------------------------------------------------------------------------
// conv1: 3 fp32 planes -> h1 NHWC bf16[128] (leaky, pad zeroed)
// block 256: 8x8 px tile x 4 oc-groups of 32. grid (32,32,HB)
// ---------------------------------------------------------------------------
__global__ __launch_bounds__(256)
void k_conv1(const float* __restrict__ p0, int s0, const float* __restrict__ p1, int s1,
             const float* __restrict__ p2, int s2, const float* __restrict__ w1,
             u16* __restrict__ h1, int b0){
    __shared__ float t3[300];
    __shared__ float wl[2700];
    const int tid = threadIdx.x;
    const int tX = blockIdx.x, tY = blockIdx.y, bz = blockIdx.z;
    const int b = b0 + bz;
    const int y0 = tY * 8 - 1, x0 = tX * 8 - 1;
    for (int idx = tid; idx < 300; idx += 256){
        int ch = idx / 100, p = idx - ch * 100;
        int r = p / 10, c = p - r * 10;
        int gy = y0 + r, gx = x0 + c;
        const float* pp = (ch == 0) ? p0 + (size_t)b * s0
                        : (ch == 1) ? p1 + (size_t)b * s1 : p2 + (size_t)b * s2;
        t3[idx] = ((unsigned)gy < 256u && (unsigned)gx < 256u) ? pp[gy * 256 + gx] : 0.f;
    }
    for (int idx = tid; idx < 2700; idx += 256) wl[idx] = w1[idx];
    __syncthreads();

    const int px = tid & 63, g = tid >> 6;          // g uniform per wave
    const int row = px >> 3, colx = px & 7;
    float iv[27];
    #pragma unroll
    for (int c3 = 0; c3 < 3; c3++)
        #pragma unroll
        for (int dr = 0; dr < 3; dr++)
            #pragma unroll
            for (int dc = 0; dc < 3; dc++)
                iv[c3 * 9 + dr * 3 + dc] = t3[c3 * 100 + (row + dr) * 10 + colx + dc];

    const int gy = tY * 8 + row, gx = tX * 8 + colx;
    u16* dst = h1 + (((size_t)bz * HW + (size_t)(gy * 256 + gx)) << 7) + g * 32;
    #pragma unroll
    for (int s = 0; s < 4; s++){
        int ov[4];
        #pragma unroll
        for (int hp = 0; hp < 4; hp++){
            u16 lo = 0, hi = 0;
            #pragma unroll
            for (int e = 0; e < 2; e++){
                int oc = g * 32 + s * 8 + hp * 2 + e;
                u16 hv = 0;
                if (oc < 100){
                    const float* wk = &wl[oc * 27];
                    float a = 0.f;
                    #pragma unroll
                    for (int q = 0; q < 27; q++) a = fmaf(wk[q], iv[q], a);
                    hv = f2bf(leaky_f(a));
                }
                if (e) hi = hv; else lo = hv;
            }
            ov[hp] = (int)lo | ((int)hi << 16);
        }
        *(int4*)(dst + s * 8) = make_int4(ov[0], ov[1], ov[2], ov[3]);
    }
}

// ---------------------------------------------------------------------------
// stage one 32-ic slab of a 34x10 halo tile (NHWC bf16[128] src) into LDS,
// row stride 40 shorts (pad -> <=2-way bank aliasing on b128 reads)
// ---------------------------------------------------------------------------
__device__ __forceinline__ void stage_slab(const u16* __restrict__ h, short* lds,
                                           int tid, int y0, int x0, size_t hbase, int ks){
    for (int idx = tid; idx < 1360; idx += 256){
        int px = idx >> 2, part = idx & 3;
        int r = px / 34, c = px - r * 34;
        int gy = y0 + r, gx = x0 + c;
        int4 v = make_int4(0, 0, 0, 0);
        if ((unsigned)gy < 256u && (unsigned)gx < 256u)
            v = *(const int4*)(h + ((hbase + (size_t)(gy * 256 + gx)) << 7) + ks * 32 + part * 8);
        *(int4*)&lds[px * 40 + part * 8] = v;
    }
}

// ---------------------------------------------------------------------------
// conv2: 100->100 3x3 as implicit GEMM, mfma_f32_16x16x32_bf16.
// block 256 (4 waves), out tile 32x8 px, per wave 4 M-tiles x 7 N-tiles.
// grid (8,32,HB). h1 -> h2 (NHWC bf16[128], leaky, pad zeroed)
// ---------------------------------------------------------------------------
__global__ __launch_bounds__(256, 2)
void k_conv2(const u16* __restrict__ h1, const u16* __restrict__ wp, u16* __restrict__ h2){
    __shared__ short lds[13600];
    const int tid = threadIdx.x;
    const int lane = tid & 63, wv = tid >> 6;
    const int quad = lane >> 4, m = lane & 15;
    const int tX = blockIdx.x, tY = blockIdx.y, bz = blockIdx.z;
    const int y0 = tY * 8 - 1, x0 = tX * 32 - 1;
    const size_t hbase = (size_t)bz << 16;

    f4v acc[4][7];
    #pragma unroll
    for (int t = 0; t < 4; t++)
        #pragma unroll
        for (int n = 0; n < 7; n++){
            acc[t][n][0] = 0.f; acc[t][n][1] = 0.f; acc[t][n][2] = 0.f; acc[t][n][3] = 0.f;
        }

    for (int ks = 0; ks < 4; ks++){
        __syncthreads();
        stage_slab(h1, lds, tid, y0, x0, hbase, ks);
        __syncthreads();
        #pragma unroll
        for (int dr = 0; dr < 3; dr++)
        #pragma unroll
        for (int dc = 0; dc < 3; dc++){
            const int off = dr * 3 + dc;
            s8v af[4];
            #pragma unroll
            for (int t = 0; t < 4; t++){
                int hrow = 2 * wv + (t >> 1) + dr;
                int hcol = (t & 1) * 16 + dc + m;
                af[t] = *(const s8v*)&lds[(hrow * 34 + hcol) * 40 + quad * 8];
            }
            const u16* wb = wp + (size_t)((off * 4 + ks) * 7) * 512 + lane * 8;
            #pragma unroll
            for (int nt = 0; nt < 7; nt++){
                s8v bf = *(const s8v*)(wb + nt * 512);
                #pragma unroll
                for (int t = 0; t < 4; t++)
                    acc[t][nt] = __builtin_amdgcn_mfma_f32_16x16x32_bf16(af[t], bf, acc[t][nt], 0, 0, 0);
            }
        }
    }

    // epilogue: D row = quad*4+reg (px in M-tile), col = m (oc in N-tile)
    #pragma unroll
    for (int t = 0; t < 4; t++){
        const int pxb = wv * 64 + t * 16 + quad * 4;
        #pragma unroll
        for (int reg = 0; reg < 4; reg++){
            int px = pxb + reg;
            int gy = tY * 8 + (px >> 5), gx = tX * 32 + (px & 31);
            size_t base = (hbase + (size_t)(gy * 256 + gx)) << 7;
            #pragma unroll
            for (int nt = 0; nt < 7; nt++){
                if (nt == 6 && m >= 4) continue;      // oc 100..111 -> pad
                h2[base + nt * 16 + m] = f2bf(leaky_f(acc[t][nt][reg]));
            }
        }
    }
    { // zero pad oc 100..127 (one px per thread)
        int gy = tY * 8 + (tid >> 5), gx = tX * 32 + (tid & 31);
        u16* p = h2 + ((hbase + (size_t)(gy * 256 + gx)) << 7);
        *(int2*)(p + 100) = make_int2(0, 0);
        *(int4*)(p + 104) = make_int4(0, 0, 0, 0);
        *(int4*)(p + 112) = make_int4(0, 0, 0, 0);
        *(int4*)(p + 120) = make_int4(0, 0, 0, 0);
    }
}

// ---------------------------------------------------------------------------
// conv3: 100->N (N=1 z-path, N=2 v-path), NHWC bf16 in, fp32 out.
// block 256, tile 32x8 px (1 px/thread). grid (8,32,HB)
// ---------------------------------------------------------------------------
template<int N>
__global__ __launch_bounds__(256)
void k_conv3(const u16* __restrict__ h2, const float* __restrict__ w3,
             const float* __restrict__ rprev, float* __restrict__ out0,
             float* __restrict__ out1, int b0){
    __shared__ short lds[13600];
    __shared__ float wl[N * 1152];
    const int tid = threadIdx.x;
    const int tX = blockIdx.x, tY = blockIdx.y, bz = blockIdx.z;
    const int y0 = tY * 8 - 1, x0 = tX * 32 - 1;
    const size_t hbase = (size_t)bz << 16;

    for (int idx = tid; idx < N * 1152; idx += 256){
        int off = idx % 9, ic = (idx / 9) & 127, n = idx / 1152;
        wl[idx] = (ic < 100) ? w3[((size_t)n * 100 + ic) * 9 + off] : 0.f;
    }
    float accn[N];
    #pragma unroll
    for (int n = 0; n < N; n++) accn[n] = 0.f;

    const int row = tid >> 5, col = tid & 31;

    for (int ks = 0; ks < 4; ks++){
        __syncthreads();
        stage_slab(h2, lds, tid, y0, x0, hbase, ks);
        __syncthreads();
        #pragma unroll
        for (int dr = 0; dr < 3; dr++)
        #pragma unroll
        for (int dc = 0; dc < 3; dc++){
            const int off = dr * 3 + dc;
            const int hb = ((row + dr) * 34 + col + dc) * 40;
            #pragma unroll
            for (int s = 0; s < 4; s++){
                s8v a = *(const s8v*)&lds[hb + s * 8];
                #pragma unroll
                for (int j = 0; j < 8; j++){
                    int ic = ks * 32 + s * 8 + j;
                    float av = bf2f((u16)a[j]);
                    #pragma unroll
                    for (int n = 0; n < N; n++)
                        accn[n] = fmaf(av, wl[(n * 128 + ic) * 9 + off], accn[n]);
                }
            }
        }
    }
    const int b = b0 + bz;
    const int gy = tY * 8 + row, gx = tX * 32 + col;
    const size_t p = (size_t)gy * 256 + gx;
    if (N == 1){
        float v = rprev[(size_t)b * HW + p] + accn[0] * 0.2f;
        out0[(size_t)b * HW + p] = v;
        out1[(size_t)b * HW + p] = v;
    } else {
        out0[((size_t)(b * 2) + 0) * HW + p] = accn[0];
        out0[((size_t)(b * 2) + 1) * HW + p] = accn[1];
    }
}

// ---------------------------------------------------------------------------
// bilinear sample, zero-outside tap masking (matches reference)
// ---------------------------------------------------------------------------
__device__ __forceinline__ float bilin(const float* __restrict__ img, float x, float y){
    float x0 = floorf(x), y0 = floorf(y);
    float wx = x - x0, wy = y - y0;
    float r = 0.f;
    #pragma unroll
    for (int dy = 0; dy < 2; dy++){
        float yi = y0 + (float)dy;
        if (yi < 0.f || yi > 255.f) continue;
        int iy = (int)yi;
        float wyv = dy ? wy : 1.f - wy;
        #pragma unroll
        for (int dx = 0; dx < 2; dx++){
            float xi = x0 + (float)dx;
            if (xi < 0.f || xi > 255.f) continue;
            int ix = (int)xi;
            float wxv = dx ? wx : 1.f - wx;
            r += wyv * wxv * img[iy * 256 + ix];
        }
    }
    return r;
}

__global__ void k_deform(const float* __restrict__ rdin, const float* __restrict__ def,
                         float* __restrict__ rdout){
    int p = blockIdx.x * 256 + threadIdx.x;
    int j = blockIdx.y;
    int b = p >> 16, q = p & 65535;
    float x = def[(size_t)(b * 2 + 0) * HW + q];
    float y = def[(size_t)(b * 2 + 1) * HW + q];
    rdout[(size_t)j * BB * HW + p] = bilin(rdin + (size_t)j * BB * HW + (size_t)b * HW, x, y);
}

__global__ void k_blur_h(const float* __restrict__ in, float* __restrict__ outb){
    __shared__ float g[51];
    __shared__ float row[306];
    __shared__ float ginv;
    int tid = threadIdx.x;
    int rid = blockIdx.x;
    int ch = rid >> 8, y = rid & 255;
    if (tid < 51){ float d = (float)tid - 25.f; g[tid] = expf(-0.005f * d * d); }
    row[tid + 25] = in[(size_t)ch * HW + y * 256 + tid];
    if (tid < 25) row[tid] = 0.f;
    if (tid >= 231) row[tid + 50] = 0.f;
    __syncthreads();
    if (tid == 0){ float s = 0.f; for (int k = 0; k < 51; k++) s += g[k]; ginv = 1.f / s; }
    __syncthreads();
    float acc = 0.f;
    for (int k = 0; k < 51; k++) acc = fmaf(g[k], row[tid + k], acc);
    outb[(size_t)ch * HW + y * 256 + tid] = acc * ginv;
}

__global__ void k_blur_v(const float* __restrict__ in, float* __restrict__ fout,
                         float* __restrict__ def){
    __shared__ float g[51];
    __shared__ float ginv;
    __shared__ float tb[82 * 64];
    int tid = threadIdx.x;
    int tX = blockIdx.x, tY = blockIdx.y, ch = blockIdx.z;
    if (tid < 51){ float d = (float)tid - 25.f; g[tid] = expf(-0.005f * d * d); }
    for (int idx = tid; idx < 82 * 64; idx += 256){
        int r = idx >> 6, c = idx & 63;
        int gy = tY * 32 + r - 25, gx = tX * 64 + c;
        tb[idx] = (gy >= 0 && gy < 256) ? in[(size_t)ch * HW + gy * 256 + gx] : 0.f;
    }
    __syncthreads();
    if (tid == 0){ float s = 0.f; for (int k = 0; k < 51; k++) s += g[k]; ginv = 1.f / s; }
    __syncthreads();
    int c = tid & 63, r0 = (tid >> 6) * 8;
    for (int k = 0; k < 8; k++){
        int r = r0 + k;
        float acc = 0.f;
        for (int t = 0; t < 51; t++) acc = fmaf(g[t], tb[(r + t) * 64 + c], acc);
        acc *= ginv;
        int y = tY * 32 + r, x = tX * 64 + c;
        fout[(size_t)ch * HW + y * 256 + x] = acc;
        def [(size_t)ch * HW + y * 256 + x] -= acc * 0.2f;
    }
}

__global__ void k_final(const float* __restrict__ def, const float* __restrict__ src,
                        const float* __restrict__ seg, const float* __restrict__ rdbase,
                        int nrd, float* __restrict__ imgout){
    int p = blockIdx.x * 256 + threadIdx.x;
    int b = p >> 16, q = p & 65535;
    float x = def[(size_t)(b * 2 + 0) * HW + q];
    float y = def[(size_t)(b * 2 + 1) * HW + q];
    float mk = bilin(seg + (size_t)b * HW, x, y);
    float s = bilin(src + (size_t)b * HW, x, y);
    float acc = 0.f;
    for (int j = 0; j < nrd; j++) acc += rdbase[(size_t)j * BB * HW + p];
    imgout[p] = s + acc * 8e-5f * mk;
}

// ---------------------------------------------------------------------------
extern "C" void kernel_launch(void* const* d_in, const int* in_sizes, int n_in,
                              void* d_out, int out_size, void* d_ws, size_t ws_size,
                              hipStream_t stream){
    const float* source = (const float*)d_in[0];
    const float* seg    = (const float*)d_in[1];
    const float* z0     = (const float*)d_in[2];
    const float* zw1    = (const float*)d_in[3];
    const float* zw2    = (const float*)d_in[4];
    const float* zw3    = (const float*)d_in[5];
    const float* vw1    = (const float*)d_in[6];
    const float* vw2    = (const float*)d_in[7];
    const float* vw3    = (const float*)d_in[8];

    float* out = (float*)d_out;
    float* images = out;                       // (6,B,1,HW)
    float* fields = out + 1572864;             // (5,B,2,HW)
    float* resid  = out + 4194304;             // (6,B,1,HW)
    float* grads  = out + 5767168;             // (6,B,2,HW)

    float* ws = (float*)d_ws;
    float* def  = ws;                          // 524288
    float* RDa  = def  + 524288;               // 1310720
    float* RDb  = RDa  + 1310720;              // 1310720
    float* vtmp = RDb  + 1310720;              // 524288
    float* btmp = vtmp + 524288;               // 524288
    u16*   wp   = (u16*)(btmp + 524288);       // 1290240 u16
    u16*   h1   = wp + 1290240;

    size_t need4 = 4194304ull * 4 + 1290240ull * 2 + 2ull * 4 * 16777216ull;
    const int HB = (ws_size >= need4) ? 4 : 1;
    u16* h2 = h1 + (size_t)HB * 8388608;       // HB*HW*128

    k_packw<<<5040, 256, 0, stream>>>(zw2, vw2, wp);
    k_init<<<1024, 256, 0, stream>>>(source, z0, images, resid, def);
    k_grad<<<1024, 256, 0, stream>>>(source, grads);

    float* RDcur = RDa;
    float* RDnxt = RDb;

    for (int i = 0; i < NL; i++){
        float* res_i  = resid  + (size_t)i * BB * HW;
        float* res_ip = resid  + (size_t)(i + 1) * BB * HW;
        float* img_i  = images + (size_t)i * BB * HW;
        float* img_ip = images + (size_t)(i + 1) * BB * HW;

        // ---- z path ----
        for (int b0 = 0; b0 < BB; b0 += HB){
            k_conv1<<<dim3(32, 32, HB), 256, 0, stream>>>(
                res_i, HW, img_i, HW, images, HW, zw1 + (size_t)i * 2700, h1, b0);
            k_conv2<<<dim3(8, 32, HB), 256, 0, stream>>>(
                h1, wp + (size_t)i * 129024, h2);
            k_conv3<1><<<dim3(8, 32, HB), 256, 0, stream>>>(
                h2, zw3 + (size_t)i * 900, res_i, res_ip,
                RDnxt + (size_t)i * BB * HW, b0);
        }

        // ---- deform previously-deformed residuals (pre-update def) ----
        if (i > 0)
            k_deform<<<dim3(1024, i), 256, 0, stream>>>(RDcur, def, RDnxt);

        // ---- v path ----
        for (int b0 = 0; b0 < BB; b0 += HB){
            k_conv1<<<dim3(32, 32, HB), 256, 0, stream>>>(
                def, 2 * HW, def + HW, 2 * HW, img_i, HW, vw1 + (size_t)i * 2700, h1, b0);
            k_conv2<<<dim3(8, 32, HB), 256, 0, stream>>>(
                h1, wp + (size_t)(NL + i) * 129024, h2);
            k_conv3<2><<<dim3(8, 32, HB), 256, 0, stream>>>(
                h2, vw3 + (size_t)i * 1800, nullptr, vtmp, nullptr, b0);
        }
        k_blur_h<<<2048, 256, 0, stream>>>(vtmp, btmp);
        k_blur_v<<<dim3(4, 8, 8), 256, 0, stream>>>(
            btmp, fields + (size_t)i * BB * 2 * HW, def);

        // ---- finalize ----
        k_final<<<1024, 256, 0, stream>>>(def, source, seg, RDnxt, i + 1, img_ip);
        k_grad<<<1024, 256, 0, stream>>>(img_ip, grads + (size_t)(i + 1) * BB * 2 * HW);

        float* t = RDcur; RDcur = RDnxt; RDnxt = t;
    }
}